// Round 6
// baseline (491.734 us; speedup 1.0000x reference)
//
#include <hip/hip_runtime.h>
#include <hip/hip_bf16.h>

typedef __bf16 bf16_t;
typedef __bf16 bf16x4 __attribute__((ext_vector_type(4)));
typedef __bf16 bf16x8 __attribute__((ext_vector_type(8)));
typedef float f32x4 __attribute__((ext_vector_type(4)));
typedef float f32x16 __attribute__((ext_vector_type(16)));

static constexpr int BB    = 2;
static constexpr int SEQ   = 2048;
static constexpr int DM    = 1024;   // D == INNER
static constexpr int NHEAD = 16;
static constexpr int HD    = 64;
static constexpr float L2E = 1.4426950408889634f;

__device__ __forceinline__ bf16x8 ld8(const bf16_t* p) {
  return *reinterpret_cast<const bf16x8*>(p);
}

// async global->LDS, 16B per lane. LDS dest is wave-uniform base + lane*16.
__device__ __forceinline__ void gl_lds16(const bf16_t* g, bf16_t* l) {
  __builtin_amdgcn_global_load_lds(
      (const __attribute__((address_space(1))) void*)g,
      (__attribute__((address_space(3))) void*)l, 16, 0, 0);
}

template <typename T> __device__ __forceinline__ T cvt_out(float v);
template <> __device__ __forceinline__ float  cvt_out<float >(float v) { return v; }
template <> __device__ __forceinline__ bf16_t cvt_out<bf16_t>(float v) { return (bf16_t)v; }

// ---------------- fused prep: 3x transpose_cast + row_prep in ONE dispatch ----------------
__device__ __forceinline__ void tc_body(const float* __restrict__ in,
                                        bf16_t* __restrict__ out,
                                        int R, int C, int bx, int by,
                                        float (*tile)[33]) {
  const int c0 = bx * 32, r0 = by * 32;
  const int tx = threadIdx.x & 31, ty = threadIdx.x >> 5;
#pragma unroll
  for (int y = ty; y < 32; y += 8)
    tile[y][tx] = in[(size_t)(r0 + y) * C + (c0 + tx)];
  __syncthreads();
#pragma unroll
  for (int y = ty; y < 32; y += 8)
    out[(size_t)(c0 + y) * R + (r0 + tx)] = (bf16_t)tile[tx][y];
}

__device__ __forceinline__ void row_prep_body(int row,
    const float* __restrict__ x, const float* __restrict__ ln_w,
    const float* __restrict__ ln_b, const int* __restrict__ mask,
    bf16_t* __restrict__ xbf, bf16_t* __restrict__ xn, float* __restrict__ maskA,
    float* red) {
  const int t = threadIdx.x;
  const float4 xv = *reinterpret_cast<const float4*>(&x[(size_t)row * DM + t * 4]);
  float s  = xv.x + xv.y + xv.z + xv.w;
  float s2 = xv.x * xv.x + xv.y * xv.y + xv.z * xv.z + xv.w * xv.w;
#pragma unroll
  for (int off = 32; off >= 1; off >>= 1) {
    s  += __shfl_xor(s,  off, 64);
    s2 += __shfl_xor(s2, off, 64);
  }
  if ((t & 63) == 0) { red[t >> 6] = s; red[4 + (t >> 6)] = s2; }
  __syncthreads();
  s  = red[0] + red[1] + red[2] + red[3];
  s2 = red[4] + red[5] + red[6] + red[7];
  const float mu   = s * (1.0f / DM);
  const float var  = s2 * (1.0f / DM) - mu * mu;
  const float rstd = rsqrtf(var + 1e-5f);
  const float4 wv = *reinterpret_cast<const float4*>(&ln_w[t * 4]);
  const float4 bv = *reinterpret_cast<const float4*>(&ln_b[t * 4]);
  union { bf16_t h[4]; uint2 u; } p0, p1;
  p0.h[0] = (bf16_t)xv.x; p0.h[1] = (bf16_t)xv.y;
  p0.h[2] = (bf16_t)xv.z; p0.h[3] = (bf16_t)xv.w;
  p1.h[0] = (bf16_t)((xv.x - mu) * rstd * wv.x + bv.x);
  p1.h[1] = (bf16_t)((xv.y - mu) * rstd * wv.y + bv.y);
  p1.h[2] = (bf16_t)((xv.z - mu) * rstd * wv.z + bv.z);
  p1.h[3] = (bf16_t)((xv.w - mu) * rstd * wv.w + bv.w);
  *reinterpret_cast<uint2*>(&xbf[(size_t)row * DM + t * 4]) = p0.u;
  *reinterpret_cast<uint2*>(&xn [(size_t)row * DM + t * 4]) = p1.u;
  if (t == 0) maskA[row] = mask[row] ? 0.0f : -1e30f;
}

__global__ __launch_bounds__(256) void prep_all(
    const float* __restrict__ x, const float* __restrict__ ln_w,
    const float* __restrict__ ln_b, const int* __restrict__ mask,
    const float* __restrict__ wq, const float* __restrict__ wkv,
    const float* __restrict__ wo,
    bf16_t* __restrict__ xbf, bf16_t* __restrict__ xn, float* __restrict__ maskA,
    bf16_t* __restrict__ wqT, bf16_t* __restrict__ wkvT, bf16_t* __restrict__ woT) {
  __shared__ float tile[32][33];
  __shared__ float red[8];
  const int bid = blockIdx.x;
  if (bid < 1024) {
    tc_body(wq, wqT, DM, DM, bid & 31, bid >> 5, tile);
  } else if (bid < 1152) {
    const int id = bid - 1024;
    tc_body(wkv, wkvT, DM, 128, id & 3, id >> 2, tile);
  } else if (bid < 2176) {
    const int id = bid - 1152;
    tc_body(wo, woT, DM, DM, id & 31, id >> 5, tile);
  } else {
    row_prep_body(bid - 2176, x, ln_w, ln_b, mask, xbf, xn, maskA, red);
  }
}

// ---- shared 128x128 MFMA core, 1-deep double-buffered LDS, 1 barrier/K-step ----
__device__ __forceinline__ void gemm_core_db(
    const bf16_t* __restrict__ A, const bf16_t* __restrict__ Bt, int K,
    int m0, int n0, bf16_t* As, bf16_t* Bs, f32x4 (&acc)[4][4]) {
  const int t = threadIdx.x, lane = t & 63, w = t >> 6;
  const int wm = (w & 1) * 64, wn = (w >> 1) * 64;
  const int l15 = lane & 15, q4 = lane >> 4;
  const int sr = lane >> 2, sc = (lane & 3) * 8;   // 16 rows x 32 cols per issue
  const bf16_t* Ap0 = A  + (size_t)(m0 + w * 32 + sr) * K + sc;
  const bf16_t* Ap1 = Ap0 + (size_t)16 * K;
  const bf16_t* Bp0 = Bt + (size_t)(n0 + w * 32 + sr) * K + sc;
  const bf16_t* Bp1 = Bp0 + (size_t)16 * K;
  const int la0 = (w * 32) * 32, la1 = (w * 32 + 16) * 32;
  // prologue: stage tile 0 into buf 0
  gl_lds16(Ap0, As + la0);
  gl_lds16(Ap1, As + la1);
  gl_lds16(Bp0, Bs + la0);
  gl_lds16(Bp1, Bs + la1);
  __syncthreads();            // drains vmcnt(0): tile 0 resident
  int buf = 0;
#pragma unroll 1
  for (int k0 = 0; k0 < K; k0 += 32) {
    const int nbuf = buf ^ 1;
    if (k0 + 32 < K) {        // stage next tile into other buffer (stays in flight)
      const int kn = k0 + 32;
      gl_lds16(Ap0 + kn, As + nbuf * (128 * 32) + la0);
      gl_lds16(Ap1 + kn, As + nbuf * (128 * 32) + la1);
      gl_lds16(Bp0 + kn, Bs + nbuf * (128 * 32) + la0);
      gl_lds16(Bp1 + kn, Bs + nbuf * (128 * 32) + la1);
    }
    const bf16_t* Asb = As + buf * (128 * 32);
    const bf16_t* Bsb = Bs + buf * (128 * 32);
    bf16x8 af[4], bfr[4];
#pragma unroll
    for (int mt = 0; mt < 4; ++mt) af[mt]  = ld8(&Asb[(wm + mt * 16 + l15) * 32 + q4 * 8]);
#pragma unroll
    for (int nt = 0; nt < 4; ++nt) bfr[nt] = ld8(&Bsb[(wn + nt * 16 + l15) * 32 + q4 * 8]);
#pragma unroll
    for (int mt = 0; mt < 4; ++mt)
#pragma unroll
      for (int nt = 0; nt < 4; ++nt)
        acc[mt][nt] = __builtin_amdgcn_mfma_f32_16x16x32_bf16(af[mt], bfr[nt], acc[mt][nt], 0, 0, 0);
    __syncthreads();          // one barrier: reads of buf done + next stage landed
    buf = nbuf;
  }
}

// ---- fused q-proj + kv-proj in one dispatch ----
__global__ __launch_bounds__(256) void gemm_qkv(
    const bf16_t* __restrict__ xn,  const bf16_t* __restrict__ wqT,  bf16_t* __restrict__ qb,
    const bf16_t* __restrict__ xbf, const bf16_t* __restrict__ wkvT,
    bf16_t* __restrict__ kkb, bf16_t* __restrict__ vTb) {
  __shared__ alignas(16) bf16_t As[2][128 * 32];
  __shared__ alignas(16) bf16_t Bs[2][128 * 32];
  const int bx = blockIdx.x;
  const bool isKV = (bx < 32);
  const int m0 = isKV ? bx * 128 : ((bx - 32) & 31) * 128;
  const int n0 = isKV ? 0 : ((bx - 32) >> 5) * 128;
  const bf16_t* A  = isKV ? xbf  : xn;
  const bf16_t* Bt = isKV ? wkvT : wqT;
  f32x4 acc[4][4] = {};
  gemm_core_db(A, Bt, DM, m0, n0, &As[0][0], &Bs[0][0], acc);

  const int lane = threadIdx.x & 63, w = threadIdx.x >> 6;
  const int wm = (w & 1) * 64, wn = (w >> 1) * 64;
  const int l15 = lane & 15, q4 = lane >> 4;
#pragma unroll
  for (int mt = 0; mt < 4; ++mt)
#pragma unroll
    for (int nt = 0; nt < 4; ++nt)
#pragma unroll
      for (int r = 0; r < 4; ++r) {
        const int gm = m0 + wm + mt * 16 + q4 * 4 + r;
        const int gn = n0 + wn + nt * 16 + l15;
        if (isKV) {
          const bf16_t ov = (bf16_t)acc[mt][nt][r];
          if (gn < HD) kkb[(size_t)gm * HD + gn] = ov;
          else vTb[((size_t)(gm >> 11) * HD + (gn - HD)) * SEQ + (gm & 2047)] = ov;
        } else {
          qb[(size_t)gm * DM + gn] = (bf16_t)(acc[mt][nt][r] * 0.125f);
        }
      }
}

// ---- out-projection: C(M,1024) fp32 = A(M,1024)*woT(1024,1024)^T ----
__global__ __launch_bounds__(256) void gemm_out(const bf16_t* __restrict__ A,
    const bf16_t* __restrict__ Bt, float* __restrict__ C, int K) {
  __shared__ alignas(16) bf16_t As[2][128 * 32];
  __shared__ alignas(16) bf16_t Bs[2][128 * 32];
  const int m0 = blockIdx.x * 128, n0 = blockIdx.y * 128;
  f32x4 acc[4][4] = {};
  gemm_core_db(A, Bt, K, m0, n0, &As[0][0], &Bs[0][0], acc);
  const int lane = threadIdx.x & 63, w = threadIdx.x >> 6;
  const int wm = (w & 1) * 64, wn = (w >> 1) * 64;
  const int l15 = lane & 15, q4 = lane >> 4;
#pragma unroll
  for (int mt = 0; mt < 4; ++mt)
#pragma unroll
    for (int nt = 0; nt < 4; ++nt)
#pragma unroll
      for (int r = 0; r < 4; ++r) {
        const int gm = m0 + wm + mt * 16 + q4 * 4 + r;
        const int gn = n0 + wn + nt * 16 + l15;
        C[(size_t)gm * DM + gn] = acc[mt][nt][r];
      }
}

// ------- flash attention v5: 32x32x16 MFMA, 1 wave = 32 queries (vs 16).
//         S^T tile D[key][query]: query = lane&31 -> softmax state lane-local
//         (no alpha/linv broadcasts); LDS K/V reads per query HALVED; P-transpose
//         = 2 shfl_xor(32) per 16-key window (8/iter vs 32/iter per 32q).
//         Staging/double-buffer identical to measured-good v3. -------
__global__ __launch_bounds__(256, 2) void flash_attn(
    const bf16_t* __restrict__ q,     // (B, SEQ, DM), head h at cols h*64..
    const bf16_t* __restrict__ kk,    // (B, SEQ, HD)
    const bf16_t* __restrict__ vT,    // (B, HD, SEQ)
    const float*  __restrict__ bias,  // (NHEAD, SEQ, SEQ)
    const float*  __restrict__ maskA, // (B, SEQ): 0 or -1e30
    bf16_t* __restrict__ aout)        // (B, SEQ, DM)
{
  const int b = blockIdx.y & 1, h = blockIdx.y >> 1;  // b fastest: bias L2 reuse
  const int i0 = blockIdx.x * 128;                    // 128 q-rows per block
  const int t = threadIdx.x, lane = t & 63, w = t >> 6;
  const int l31 = lane & 31, hi = lane >> 5;

  __shared__ alignas(16) bf16_t Ks[2][64][72];   // [key][dh]
  __shared__ alignas(16) bf16_t Vs[2][64][72];   // [dh][key]

  // Q fragments (B-operand: B[k=dh][n=query=l31]); wave w owns queries w*32..+31
  const int qrow = i0 + w * 32 + l31;
  const bf16_t* qp = &q[((size_t)b * SEQ + qrow) * DM + h * HD];
  bf16x8 qf[4];
#pragma unroll
  for (int st = 0; st < 4; ++st) qf[st] = ld8(qp + st * 16 + hi * 8);

  f32x16 o0 = {}, o1 = {};            // O^T accum: d-tiles 0..31 / 32..63
  float m_run = -1e30f, l_run = 0.0f;

  const float* bias_p = bias + (size_t)h * SEQ * SEQ + (size_t)qrow * SEQ;
  const float* mask_p = maskA + b * SEQ;
  const int boff = 4 * hi;            // lane's key sub-offset within each 8-group

  const int sr = t >> 2, sc = (t & 3) * 16;
  const bf16_t* kp = &kk[((size_t)b * SEQ + sr) * HD + sc];
  const bf16_t* vp = &vT[((size_t)b * HD + sr) * SEQ + sc];

  // prologue: tile 0 into buf 0, fused bias+mask iter-0 into regs
  uint4 kr0 = *reinterpret_cast<const uint4*>(kp);
  uint4 kr1 = *reinterpret_cast<const uint4*>(kp + 8);
  uint4 vr0 = *reinterpret_cast<const uint4*>(vp);
  uint4 vr1 = *reinterpret_cast<const uint4*>(vp + 8);
  f32x4 bm[2][4];
#pragma unroll
  for (int kt = 0; kt < 2; ++kt)
#pragma unroll
    for (int g = 0; g < 4; ++g) {
      const int ko = kt * 32 + g * 8 + boff;
      bm[kt][g] = *reinterpret_cast<const f32x4*>(bias_p + ko)
                + *reinterpret_cast<const f32x4*>(mask_p + ko);
    }
  *reinterpret_cast<uint4*>(&Ks[0][sr][sc])     = kr0;
  *reinterpret_cast<uint4*>(&Ks[0][sr][sc + 8]) = kr1;
  *reinterpret_cast<uint4*>(&Vs[0][sr][sc])     = vr0;
  *reinterpret_cast<uint4*>(&Vs[0][sr][sc + 8]) = vr1;
  __syncthreads();

#pragma unroll 1
  for (int it = 0; it < SEQ / 64; ++it) {
    const int buf = it & 1;
    const int j1 = (it + 1) * 64;
    const bool more = (j1 < SEQ);
    if (more) {   // prefetch next K/V tile into regs (global, async)
      kr0 = *reinterpret_cast<const uint4*>(kp + (size_t)j1 * HD);
      kr1 = *reinterpret_cast<const uint4*>(kp + (size_t)j1 * HD + 8);
      vr0 = *reinterpret_cast<const uint4*>(vp + j1);
      vr1 = *reinterpret_cast<const uint4*>(vp + j1 + 8);
    }

    // S^T: D[m=key][n=query] = K·Q^T. Two 32-key tiles, 4 dh-steps of 16.
    f32x16 s0 = {}, s1 = {};
#pragma unroll
    for (int st = 0; st < 4; ++st) {
      const bf16x8 kf0 = ld8(&Ks[buf][l31]     [st * 16 + hi * 8]);
      const bf16x8 kf1 = ld8(&Ks[buf][32 + l31][st * 16 + hi * 8]);
      s0 = __builtin_amdgcn_mfma_f32_32x32x16_bf16(kf0, qf[st], s0, 0, 0, 0);
      s1 = __builtin_amdgcn_mfma_f32_32x32x16_bf16(kf1, qf[st], s1, 0, 0, 0);
    }

    // bias+mask add; per-query (lane-local) max over this lane's 32 keys
    float mx = -1e30f;
#pragma unroll
    for (int r = 0; r < 16; ++r) {
      s0[r] = s0[r] + bm[0][r >> 2][r & 3];
      s1[r] = s1[r] + bm[1][r >> 2][r & 3];
      mx = fmaxf(mx, fmaxf(s0[r], s1[r]));
    }
    if (more) {   // prefetch next fused bias+mask
#pragma unroll
      for (int kt = 0; kt < 2; ++kt)
#pragma unroll
        for (int g = 0; g < 4; ++g) {
          const int ko = j1 + kt * 32 + g * 8 + boff;
          bm[kt][g] = *reinterpret_cast<const f32x4*>(bias_p + ko)
                    + *reinterpret_cast<const f32x4*>(mask_p + ko);
        }
    }
    // partner lane (l31, hi^1) holds the other 32 keys of the same query
    mx = fmaxf(mx, __shfl_xor(mx, 32, 64));
    const float mnew  = fmaxf(m_run, mx);
    const float alpha = __builtin_amdgcn_exp2f((m_run - mnew) * L2E);
    const float cc    = -mnew * L2E;
    m_run = mnew;

    float su = 0.0f;
#pragma unroll
    for (int r = 0; r < 16; ++r) {
      s0[r] = __builtin_amdgcn_exp2f(__builtin_fmaf(s0[r], L2E, cc));
      s1[r] = __builtin_amdgcn_exp2f(__builtin_fmaf(s1[r], L2E, cc));
      su += s0[r] + s1[r];
    }
    su += __shfl_xor(su, 32, 64);
    l_run = l_run * alpha + su;

    // rescale O (alpha lane-local: this lane's query)
#pragma unroll
    for (int r = 0; r < 16; ++r) { o0[r] *= alpha; o1[r] *= alpha; }

    // build P^T B-frags: window w16 = keys [w16*16, +16). Lane holds groups
    // A: keys w*16+4hi+0..3 (regs 8*st+0..3), B: keys w*16+8+4hi+0..3 (regs +4..7).
    // Needs keys w*16 + 8*hi + 0..7 -> exchange one packed group with partner.
    bf16x8 pf[4];
#pragma unroll
    for (int w16 = 0; w16 < 4; ++w16) {
      const int st2 = w16 & 1;
      const f32x16& sv = (w16 < 2) ? s0 : s1;
      union { bf16_t hh[4]; unsigned u[2]; } A, Bu;
#pragma unroll
      for (int j = 0; j < 4; ++j) {
        A.hh[j]  = (bf16_t)sv[st2 * 8 + j];
        Bu.hh[j] = (bf16_t)sv[st2 * 8 + 4 + j];
      }
      const unsigned x0 = hi ? A.u[0] : Bu.u[0];
      const unsigned x1 = hi ? A.u[1] : Bu.u[1];
      const unsigned y0 = (unsigned)__shfl_xor((int)x0, 32, 64);
      const unsigned y1 = (unsigned)__shfl_xor((int)x1, 32, 64);
      union { unsigned u[4]; bf16x8 v; } P;
      P.u[0] = hi ? y0 : A.u[0];
      P.u[1] = hi ? y1 : A.u[1];
      P.u[2] = hi ? Bu.u[0] : y0;
      P.u[3] = hi ? Bu.u[1] : y1;
      pf[w16] = P.v;
    }

    // PV: O^T[d][q] += V^T[d][key] * P^T[key][q], 4 key-steps of 16, 2 d-tiles
#pragma unroll
    for (int w16 = 0; w16 < 4; ++w16) {
      const bf16x8 vf0 = ld8(&Vs[buf][l31]     [w16 * 16 + hi * 8]);
      const bf16x8 vf1 = ld8(&Vs[buf][32 + l31][w16 * 16 + hi * 8]);
      o0 = __builtin_amdgcn_mfma_f32_32x32x16_bf16(vf0, pf[w16], o0, 0, 0, 0);
      o1 = __builtin_amdgcn_mfma_f32_32x32x16_bf16(vf1, pf[w16], o1, 0, 0, 0);
    }

    if (more) {   // store prefetched tile into the other buffer
      *reinterpret_cast<uint4*>(&Ks[buf ^ 1][sr][sc])     = kr0;
      *reinterpret_cast<uint4*>(&Ks[buf ^ 1][sr][sc + 8]) = kr1;
      *reinterpret_cast<uint4*>(&Vs[buf ^ 1][sr][sc])     = vr0;
      *reinterpret_cast<uint4*>(&Vs[buf ^ 1][sr][sc + 8]) = vr1;
    }
    __syncthreads();
  }

  // epilogue: lane-local 1/l; O^T reg r -> d = dt*32 + (r&3)+8*(r>>2)+4*hi
  const float linv = 1.0f / l_run;
  bf16_t* dst = &aout[((size_t)b * SEQ + qrow) * DM + h * HD];
#pragma unroll
  for (int g = 0; g < 4; ++g) {
    union { bf16_t hh[4]; uint2 u2; } E0, E1;
#pragma unroll
    for (int j = 0; j < 4; ++j) {
      E0.hh[j] = (bf16_t)(o0[g * 4 + j] * linv);
      E1.hh[j] = (bf16_t)(o1[g * 4 + j] * linv);
    }
    *reinterpret_cast<uint2*>(dst + g * 8 + 4 * hi)      = E0.u2;
    *reinterpret_cast<uint2*>(dst + 32 + g * 8 + 4 * hi) = E1.u2;
  }
}

extern "C" void kernel_launch(void* const* d_in, const int* in_sizes, int n_in,
                              void* d_out, int out_size, void* d_ws, size_t ws_size,
                              hipStream_t stream) {
  const float* x         = (const float*)d_in[0];
  const float* attn_bias = (const float*)d_in[1];
  const float* ln_w      = (const float*)d_in[2];
  const float* ln_b      = (const float*)d_in[3];
  const float* wq        = (const float*)d_in[4];
  const float* wkv       = (const float*)d_in[5];
  const float* wo        = (const float*)d_in[6];
  const int*   mask      = (const int*)d_in[7];
  float* out = (float*)d_out;

  char* ws = (char*)d_ws;
  size_t off = 0;
  auto alloc = [&](size_t bytes) {
    char* p = ws + off;
    off += (bytes + 255) & ~(size_t)255;
    return p;
  };
  bf16_t* xbf   = (bf16_t*)alloc((size_t)BB * SEQ * DM * 2);
  bf16_t* xn    = (bf16_t*)alloc((size_t)BB * SEQ * DM * 2);
  bf16_t* wqT   = (bf16_t*)alloc((size_t)DM * DM * 2);
  bf16_t* wkvT  = (bf16_t*)alloc((size_t)2 * HD * DM * 2);
  bf16_t* woT   = (bf16_t*)alloc((size_t)DM * DM * 2);
  bf16_t* qb    = (bf16_t*)alloc((size_t)BB * SEQ * DM * 2);
  bf16_t* kkb   = (bf16_t*)alloc((size_t)BB * SEQ * HD * 2);
  bf16_t* vTb   = (bf16_t*)alloc((size_t)BB * HD * SEQ * 2);
  bf16_t* aoutb = (bf16_t*)alloc((size_t)BB * SEQ * DM * 2);
  float*  maskA = (float*)alloc((size_t)BB * SEQ * 4);

  // one prep dispatch: wq/wkv/wo transposes + layernorm row prep
  prep_all<<<6272, 256, 0, stream>>>(x, ln_w, ln_b, mask, wq, wkv, wo,
                                     xbf, xn, maskA, wqT, wkvT, woT);
  // fused: blocks 0..31 kv = x @ wkv -> K,(V^T); blocks 32..287 q = xn @ wq * 0.125
  gemm_qkv<<<288, 256, 0, stream>>>(xn, wqT, qb, xbf, wkvT, kkb, vTb);
  flash_attn<<<dim3(SEQ / 128, BB * NHEAD), 256, 0, stream>>>(qb, kkb, vTb, attn_bias,
                                                              maskA, aoutb);
  // out = aout @ wo (fp32 output)
  gemm_out<<<dim3(32, 8), 256, 0, stream>>>(aoutb, woT, out, DM);
}